// Round 1
// baseline (529.673 us; speedup 1.0000x reference)
//
#include <hip/hip_runtime.h>
#include <cmath>

// GaussCRF on MI355X.
// B=2, C=21, H=W=512, blur=4 -> h=w=128, K=11 (121 shifts), 5 iterations.
//
// Structure:
//  1. pool_img_k : img*col_schan avg-pooled 4x4 -> cf [B,3,128,128]
//  2. gauss_k    : merged kernel g [B,121,128,128].
//                  pos part is analytically constant per shift:
//                  pooled pos feat = pos_sdims*(4X+1.5) so diff = 4*pos_sdims*dx.
//  3. lsm_k      : lg_unary = log_softmax(unary, axis=C); pred (=d_out) init.
//  per iter:
//  4. pool_pred_k: pred 512^2 -> p 128^2
//  5. msg_k      : msg[b,c,X,Y] = sum_ij g[b,ij,X,Y]*p[b,c,X+di,Y+dj]
//                  (channel-split by 7 for occupancy + 3x g reuse per load)
//  6. combine_k  : bilinear 4x upsample (align_corners=False, clamped taps ==
//                  jax renormalized triangle kernel) + (1-w)*lg + w*msg
//                  + channel softmax except last iter. Writes pred (d_out).

#define BB 2
#define CC 21
#define HH 512
#define WW 512
#define HP 128
#define WP 128
#define KF 11
#define SPAN 5
#define NB 121
#define NITER 5
#define CG 7
#define NGRP 3

__global__ void pool_img_k(const float* __restrict__ img,
                           const float* __restrict__ col_schan,
                           float* __restrict__ cf) {
    int idx = blockIdx.x * blockDim.x + threadIdx.x;
    if (idx >= BB*3*HP*WP) return;
    int Y  = idx & (WP-1);
    int X  = (idx >> 7) & (HP-1);
    int bc = idx >> 14;                       // b*3 + c
    const float* base = img + ((size_t)bc*HH + X*4)*WW + Y*4;
    float s = 0.f;
    #pragma unroll
    for (int i = 0; i < 4; ++i)
        #pragma unroll
        for (int j = 0; j < 4; ++j)
            s += base[i*WW + j];
    cf[idx] = s * (1.f/16.f) * col_schan[0];
}

__global__ void gauss_k(const float* __restrict__ cf,
                        const float* __restrict__ pos_sdims,
                        const float* __restrict__ pos_compat,
                        const float* __restrict__ col_compat,
                        float* __restrict__ g) {
    int idx = blockIdx.x * blockDim.x + threadIdx.x;
    if (idx >= BB*HP*WP) return;
    int Y = idx & (WP-1);
    int X = (idx >> 7) & (HP-1);
    int b = idx >> 14;
    const float* cb = cf + (size_t)b*3*HP*WP;
    int o0 = X*WP + Y;
    float f0 = cb[o0];
    float f1 = cb[HP*WP + o0];
    float f2 = cb[2*HP*WP + o0];
    float ps  = 4.f * pos_sdims[0];
    float ps2 = ps * ps;
    float pc = pos_compat[0], cc = col_compat[0];
    float* gb = g + (size_t)b*NB*HP*WP + o0;
    for (int di = -SPAN; di <= SPAN; ++di) {
        for (int dj = -SPAN; dj <= SPAN; ++dj) {
            int ij = (di+SPAN)*KF + (dj+SPAN);
            int Xn = X + di, Yn = Y + dj;
            float val = 0.f;
            if (Xn >= 0 && Xn < HP && Yn >= 0 && Yn < WP) {
                int o = Xn*WP + Yn;
                float d0 = cb[o]           - f0;
                float d1 = cb[HP*WP + o]   - f1;
                float d2 = cb[2*HP*WP + o] - f2;
                float cd2 = d0*d0 + d1*d1 + d2*d2;
                float pd2 = ps2 * (float)(di*di + dj*dj);
                val = pc * expf(-0.5f*pd2) + cc * expf(-0.5f*cd2);
            }
            gb[(size_t)ij*HP*WP] = val;
        }
    }
}

__global__ void lsm_k(const float* __restrict__ unary,
                      float* __restrict__ lg,
                      float* __restrict__ pred) {
    int idx = blockIdx.x * blockDim.x + threadIdx.x;
    if (idx >= BB*HH*WW) return;
    int xy = idx & (HH*WW - 1);               // HH*WW = 2^18
    int b  = idx >> 18;
    const float* ub = unary + (size_t)b*CC*HH*WW + xy;
    float v[CC];
    float m = -1e30f;
    #pragma unroll
    for (int c = 0; c < CC; ++c) { v[c] = ub[(size_t)c*HH*WW]; m = fmaxf(m, v[c]); }
    float s = 0.f;
    #pragma unroll
    for (int c = 0; c < CC; ++c) s += expf(v[c]-m);
    float ls = m + logf(s);
    float* lb = lg   + (size_t)b*CC*HH*WW + xy;
    float* pb = pred + (size_t)b*CC*HH*WW + xy;
    #pragma unroll
    for (int c = 0; c < CC; ++c) {
        float t = v[c] - ls;
        lb[(size_t)c*HH*WW] = t;
        pb[(size_t)c*HH*WW] = t;
    }
}

__global__ void pool_pred_k(const float* __restrict__ pred, float* __restrict__ p) {
    int idx = blockIdx.x * blockDim.x + threadIdx.x;
    if (idx >= BB*CC*HP*WP) return;
    int Y  = idx & (WP-1);
    int X  = (idx >> 7) & (HP-1);
    int bc = idx >> 14;                       // b*CC + c
    const float* base = pred + ((size_t)bc*HH + X*4)*WW + Y*4;
    float s = 0.f;
    #pragma unroll
    for (int i = 0; i < 4; ++i)
        #pragma unroll
        for (int j = 0; j < 4; ++j)
            s += base[i*WW + j];
    p[idx] = s * (1.f/16.f);
}

__global__ void msg_k(const float* __restrict__ g,
                      const float* __restrict__ p,
                      float* __restrict__ msg) {
    int idx = blockIdx.x * blockDim.x + threadIdx.x;
    if (idx >= BB*HP*WP) return;
    int c0 = blockIdx.y * CG;
    int Y = idx & (WP-1);
    int X = (idx >> 7) & (HP-1);
    int b = idx >> 14;
    const float* gb = g + (size_t)b*NB*HP*WP + X*WP + Y;
    const float* pb = p + ((size_t)b*CC + c0)*HP*WP;
    float acc[CG];
    #pragma unroll
    for (int c = 0; c < CG; ++c) acc[c] = 0.f;
    for (int di = -SPAN; di <= SPAN; ++di) {
        int Xn = X + di;
        if (Xn < 0 || Xn >= HP) continue;     // g is 0 there anyway
        for (int dj = -SPAN; dj <= SPAN; ++dj) {
            int Yn = Y + dj;
            if (Yn < 0 || Yn >= WP) continue;
            int ij = (di+SPAN)*KF + (dj+SPAN);
            float gv = gb[(size_t)ij*HP*WP];
            const float* pp = pb + Xn*WP + Yn;
            #pragma unroll
            for (int c = 0; c < CG; ++c)
                acc[c] = fmaf(gv, pp[(size_t)c*HP*WP], acc[c]);
        }
    }
    float* mb = msg + ((size_t)b*CC + c0)*HP*WP + X*WP + Y;
    #pragma unroll
    for (int c = 0; c < CG; ++c)
        mb[(size_t)c*HP*WP] = acc[c];
}

__global__ void combine_k(const float* __restrict__ msg,
                          const float* __restrict__ lg,
                          const float* __restrict__ weight,
                          float* __restrict__ pred,
                          int do_softmax) {
    int idx = blockIdx.x * blockDim.x + threadIdx.x;
    if (idx >= BB*HH*WW) return;
    int y = idx & (WW-1);
    int x = (idx >> 9) & (HH-1);
    int b = idx >> 18;
    // half-pixel bilinear, 4x upsample: u = x/4 - 0.375, taps clamped
    float u  = x*0.25f - 0.375f;
    int   i0 = (int)floorf(u);
    float fx = u - (float)i0;
    int X0 = i0 < 0 ? 0 : i0;
    int X1 = (i0+1 > HP-1) ? HP-1 : i0+1;
    float v  = y*0.25f - 0.375f;
    int   j0 = (int)floorf(v);
    float fy = v - (float)j0;
    int Y0 = j0 < 0 ? 0 : j0;
    int Y1 = (j0+1 > WP-1) ? WP-1 : j0+1;
    float w00 = (1.f-fx)*(1.f-fy), w01 = (1.f-fx)*fy;
    float w10 = fx*(1.f-fy),       w11 = fx*fy;
    int o00 = X0*WP+Y0, o01 = X0*WP+Y1, o10 = X1*WP+Y0, o11 = X1*WP+Y1;
    const float* mb = msg + (size_t)b*CC*HP*WP;
    const float* lb = lg  + (size_t)b*CC*HH*WW + x*WW + y;
    float wt = weight[0];
    float uw = 1.0f - wt;                      // UNARY_WEIGHT = 1.0
    float val[CC];
    #pragma unroll
    for (int c = 0; c < CC; ++c) {
        const float* mc = mb + (size_t)c*HP*WP;
        float mu = w00*mc[o00] + w01*mc[o01] + w10*mc[o10] + w11*mc[o11];
        val[c] = uw*lb[(size_t)c*HH*WW] + wt*mu;
    }
    float* pb = pred + (size_t)b*CC*HH*WW + x*WW + y;
    if (do_softmax) {
        float m = -1e30f;
        #pragma unroll
        for (int c = 0; c < CC; ++c) m = fmaxf(m, val[c]);
        float s = 0.f;
        #pragma unroll
        for (int c = 0; c < CC; ++c) { float e = expf(val[c]-m); val[c] = e; s += e; }
        float inv = 1.f/s;
        #pragma unroll
        for (int c = 0; c < CC; ++c) pb[(size_t)c*HH*WW] = val[c]*inv;
    } else {
        #pragma unroll
        for (int c = 0; c < CC; ++c) pb[(size_t)c*HH*WW] = val[c];
    }
}

extern "C" void kernel_launch(void* const* d_in, const int* in_sizes, int n_in,
                              void* d_out, int out_size, void* d_ws, size_t ws_size,
                              hipStream_t stream) {
    const float* unary      = (const float*)d_in[0];
    const float* img        = (const float*)d_in[1];
    const float* pos_sdims  = (const float*)d_in[2];
    const float* col_schan  = (const float*)d_in[3];
    const float* pos_compat = (const float*)d_in[4];
    const float* col_compat = (const float*)d_in[5];
    const float* weight     = (const float*)d_in[6];
    float* pred = (float*)d_out;               // pred lives in d_out
    float* ws   = (float*)d_ws;

    size_t o = 0;
    float* lg  = ws + o;  o += (size_t)BB*CC*HH*WW;   // 44 MB
    float* g   = ws + o;  o += (size_t)BB*NB*HP*WP;   // 16 MB
    float* cf  = ws + o;  o += (size_t)BB*3*HP*WP;    // 0.4 MB
    float* p   = ws + o;  o += (size_t)BB*CC*HP*WP;   // 2.75 MB
    float* msg = ws + o;                               // 2.75 MB

    const int TB = 256;
    hipLaunchKernelGGL(pool_img_k, dim3((BB*3*HP*WP+TB-1)/TB), dim3(TB), 0, stream,
                       img, col_schan, cf);
    hipLaunchKernelGGL(gauss_k, dim3((BB*HP*WP+TB-1)/TB), dim3(TB), 0, stream,
                       cf, pos_sdims, pos_compat, col_compat, g);
    hipLaunchKernelGGL(lsm_k, dim3((BB*HH*WW+TB-1)/TB), dim3(TB), 0, stream,
                       unary, lg, pred);
    for (int it = 0; it < NITER; ++it) {
        hipLaunchKernelGGL(pool_pred_k, dim3((BB*CC*HP*WP+TB-1)/TB), dim3(TB), 0, stream,
                           pred, p);
        hipLaunchKernelGGL(msg_k, dim3((BB*HP*WP+TB-1)/TB, NGRP), dim3(TB), 0, stream,
                           g, p, msg);
        hipLaunchKernelGGL(combine_k, dim3((BB*HH*WW+TB-1)/TB), dim3(TB), 0, stream,
                           msg, lg, weight, pred, (it != NITER-1) ? 1 : 0);
    }
}

// Round 2
// 366.341 us; speedup vs baseline: 1.4458x; 1.4458x over previous
//
#include <hip/hip_runtime.h>
#include <cmath>

// GaussCRF on MI355X — round 2.
// B=2, C=21, H=W=512, blur=4 -> h=w=128, K=11 (121 shifts), 5 iterations.
//
// Key structure vs round 1:
//  * Intermediate full-res pred is NEVER materialized: combine+softmax+pool
//    fused (iters 0..3 write only pooled p, 2.75 MB). pool_pred_k eliminated.
//  * lsm_pool_k: log_softmax + 4x4 pool fused via __shfl_xor butterflies
//    (4x4 pixel blocks live on lane bits {0,1,4,5} of a 64-lane wave).
//  * msg_k: LDS-staged p tile (7 channels x 18x26 halo), 768 blocks.
//  * gauss_k: one thread per output element (4M threads).

#define BB 2
#define CC 21
#define HH 512
#define WW 512
#define HP 128
#define WP 128
#define KF 11
#define SPAN 5
#define NB 121
#define NITER 5
#define PLF (HH*WW)
#define PLP (HP*WP)

__global__ void pool_img_k(const float* __restrict__ img,
                           const float* __restrict__ col_schan,
                           float* __restrict__ cf) {
    int idx = blockIdx.x * blockDim.x + threadIdx.x;
    if (idx >= BB*3*PLP) return;
    int Y  = idx & (WP-1);
    int X  = (idx >> 7) & (HP-1);
    int bc = idx >> 14;                       // b*3 + c
    const float* base = img + ((size_t)bc*HH + X*4)*WW + Y*4;
    float s = 0.f;
    #pragma unroll
    for (int i = 0; i < 4; ++i)
        #pragma unroll
        for (int j = 0; j < 4; ++j)
            s += base[i*WW + j];
    cf[idx] = s * (1.f/16.f) * col_schan[0];
}

// one thread per (b, ij, X, Y)
__global__ void gauss_k(const float* __restrict__ cf,
                        const float* __restrict__ pos_sdims,
                        const float* __restrict__ pos_compat,
                        const float* __restrict__ col_compat,
                        float* __restrict__ g) {
    int idx = blockIdx.x * blockDim.x + threadIdx.x;
    if (idx >= BB*NB*PLP) return;
    int xy = idx & (PLP-1);
    int t  = idx >> 14;
    int ij = t % NB;
    int b  = t / NB;
    int Y = xy & (WP-1);
    int X = xy >> 7;
    int di = ij / KF - SPAN;
    int dj = ij % KF - SPAN;
    int Xn = X + di, Yn = Y + dj;
    float val = 0.f;
    if (Xn >= 0 && Xn < HP && Yn >= 0 && Yn < WP) {
        const float* cb = cf + (size_t)b*3*PLP;
        int o0 = xy, o = Xn*WP + Yn;
        float d0 = cb[o]         - cb[o0];
        float d1 = cb[PLP + o]   - cb[PLP + o0];
        float d2 = cb[2*PLP + o] - cb[2*PLP + o0];
        float cd2 = d0*d0 + d1*d1 + d2*d2;
        float ps  = 4.f * pos_sdims[0];
        float pd2 = ps*ps * (float)(di*di + dj*dj);
        val = pos_compat[0] * expf(-0.5f*pd2) + col_compat[0] * expf(-0.5f*cd2);
    }
    g[idx] = val;
}

// log_softmax over C, write lg, and 4x4-pool lg -> p0 (pred@it0 == lg).
__global__ __launch_bounds__(256) void lsm_pool_k(const float* __restrict__ unary,
                                                  float* __restrict__ lg,
                                                  float* __restrict__ p) {
    int b  = blockIdx.z;
    int tx = blockIdx.y, ty = blockIdx.x;     // 32 x 32 tiles of 16x16
    int l  = threadIdx.x;
    int row = l >> 4, col = l & 15;
    int x = tx*16 + row, y = ty*16 + col;
    size_t base = (size_t)b*CC*PLF + (size_t)x*WW + y;
    float v[CC];
    float m = -1e30f;
    #pragma unroll
    for (int c = 0; c < CC; ++c) { v[c] = unary[base + (size_t)c*PLF]; m = fmaxf(m, v[c]); }
    float s = 0.f;
    #pragma unroll
    for (int c = 0; c < CC; ++c) s += expf(v[c]-m);
    float ls = m + logf(s);
    int X = tx*4 + (row>>2), Y = ty*4 + (col>>2);
    size_t pb = (size_t)b*CC*PLP + (size_t)X*WP + Y;
    bool wr = (l & 51) == 0;                  // bits {0,1,4,5} == 0
    #pragma unroll
    for (int c = 0; c < CC; ++c) {
        float t = v[c] - ls;
        lg[base + (size_t)c*PLF] = t;
        float sm = t;
        sm += __shfl_xor(sm, 1);
        sm += __shfl_xor(sm, 2);
        sm += __shfl_xor(sm, 16);
        sm += __shfl_xor(sm, 32);
        if (wr) p[pb + (size_t)c*PLP] = sm * (1.f/16.f);
    }
}

// msg[b,c,X,Y] = sum_ij g[b,ij,X,Y] * p[b,c,X+di,Y+dj], LDS-staged p tile.
// block: 8x16 output tile, 7 channels; grid (8, 16, BB*3).
__global__ __launch_bounds__(128) void msg_k(const float* __restrict__ g,
                                             const float* __restrict__ p,
                                             float* __restrict__ msg) {
    int bz = blockIdx.z;
    int b = bz / 3, cg = bz % 3;
    int c0 = cg * 7;
    int tx = blockIdx.y;                      // 0..15 (rows of 8)
    int ty = blockIdx.x;                      // 0..7  (cols of 16)
    int l = threadIdx.x;                      // 0..127
    int x = l >> 4;                           // 0..7
    int y = l & 15;                           // 0..15
    __shared__ float pt[7][18][26];
    const float* pb = p + ((size_t)b*CC + c0)*PLP;
    int X0 = tx*8 - SPAN, Y0 = ty*16 - SPAN;
    for (int t = l; t < 7*18*26; t += 128) {
        int c  = t / (18*26);
        int rr = (t / 26) % 18;
        int cl = t % 26;
        int gX = X0 + rr, gY = Y0 + cl;
        float v = 0.f;
        if (gX >= 0 && gX < HP && gY >= 0 && gY < WP)
            v = pb[(size_t)c*PLP + gX*WP + gY];
        pt[c][rr][cl] = v;
    }
    __syncthreads();
    int Xg = tx*8 + x, Yg = ty*16 + y;
    const float* gq = g + (size_t)b*NB*PLP + Xg*WP + Yg;
    float acc[7];
    #pragma unroll
    for (int c = 0; c < 7; ++c) acc[c] = 0.f;
    #pragma unroll 1
    for (int di = 0; di < KF; ++di) {
        #pragma unroll
        for (int dj = 0; dj < KF; ++dj) {
            float gv = gq[(size_t)(di*KF + dj)*PLP];
            #pragma unroll
            for (int c = 0; c < 7; ++c)
                acc[c] = fmaf(gv, pt[c][x+di][y+dj], acc[c]);
        }
    }
    float* mb = msg + ((size_t)b*CC + c0)*PLP + (size_t)Xg*WP + Yg;
    #pragma unroll
    for (int c = 0; c < 7; ++c)
        mb[(size_t)c*PLP] = acc[c];
}

// bilinear 4x upsample of msg + (1-w)*lg + w*mu; then
//   last==0: softmax over C and 4x4 pool -> p (128^2)
//   last==1: write pred (=d_out) at 512^2, no softmax
__global__ __launch_bounds__(256) void combine_k(const float* __restrict__ msg,
                                                 const float* __restrict__ lg,
                                                 const float* __restrict__ weight,
                                                 float* __restrict__ p,
                                                 float* __restrict__ pred,
                                                 int last) {
    int b  = blockIdx.z;
    int tx = blockIdx.y, ty = blockIdx.x;     // 32 x 32 tiles of 16x16
    int l  = threadIdx.x;
    int row = l >> 4, col = l & 15;
    __shared__ float ms[CC][6][6];
    const float* mb = msg + (size_t)b*CC*PLP;
    for (int t = l; t < CC*36; t += 256) {
        int c = t / 36, rr = (t / 6) % 6, cl = t % 6;
        int gX = tx*4 - 1 + rr; gX = gX < 0 ? 0 : (gX > HP-1 ? HP-1 : gX);
        int gY = ty*4 - 1 + cl; gY = gY < 0 ? 0 : (gY > WP-1 ? WP-1 : gY);
        ms[c][rr][cl] = mb[(size_t)c*PLP + gX*WP + gY];
    }
    __syncthreads();
    // half-pixel bilinear: u = x/4 - 0.375; fx per (x%4): {0.625,0.875,0.125,0.375}
    const float fw0 = 0.625f, fw1 = 0.875f, fw2 = 0.125f, fw3 = 0.375f;
    int r  = row & 3, q  = row >> 2;
    int rc = col & 3, qc = col >> 2;
    float fx = (r  == 0) ? fw0 : (r  == 1) ? fw1 : (r  == 2) ? fw2 : fw3;
    float fy = (rc == 0) ? fw0 : (rc == 1) ? fw1 : (rc == 2) ? fw2 : fw3;
    int i0 = q  + (r  >> 1);                  // local row in staged 6x6
    int j0 = qc + (rc >> 1);
    float w00 = (1.f-fx)*(1.f-fy), w01 = (1.f-fx)*fy;
    float w10 = fx*(1.f-fy),       w11 = fx*fy;
    int x = tx*16 + row, y = ty*16 + col;
    size_t base = (size_t)b*CC*PLF + (size_t)x*WW + y;
    float wt = weight[0], uw = 1.f - wt;      // UNARY_WEIGHT = 1.0
    float val[CC];
    #pragma unroll
    for (int c = 0; c < CC; ++c) {
        float mu = w00*ms[c][i0][j0]   + w01*ms[c][i0][j0+1]
                 + w10*ms[c][i0+1][j0] + w11*ms[c][i0+1][j0+1];
        val[c] = uw*lg[base + (size_t)c*PLF] + wt*mu;
    }
    if (!last) {
        float m = -1e30f;
        #pragma unroll
        for (int c = 0; c < CC; ++c) m = fmaxf(m, val[c]);
        float s = 0.f;
        #pragma unroll
        for (int c = 0; c < CC; ++c) { float e = expf(val[c]-m); val[c] = e; s += e; }
        float inv = 1.f/s;
        int X = tx*4 + q, Y = ty*4 + qc;
        size_t pb = (size_t)b*CC*PLP + (size_t)X*WP + Y;
        bool wr = (l & 51) == 0;
        #pragma unroll
        for (int c = 0; c < CC; ++c) {
            float sm = val[c]*inv;
            sm += __shfl_xor(sm, 1);
            sm += __shfl_xor(sm, 2);
            sm += __shfl_xor(sm, 16);
            sm += __shfl_xor(sm, 32);
            if (wr) p[pb + (size_t)c*PLP] = sm * (1.f/16.f);
        }
    } else {
        #pragma unroll
        for (int c = 0; c < CC; ++c)
            pred[base + (size_t)c*PLF] = val[c];
    }
}

extern "C" void kernel_launch(void* const* d_in, const int* in_sizes, int n_in,
                              void* d_out, int out_size, void* d_ws, size_t ws_size,
                              hipStream_t stream) {
    const float* unary      = (const float*)d_in[0];
    const float* img        = (const float*)d_in[1];
    const float* pos_sdims  = (const float*)d_in[2];
    const float* col_schan  = (const float*)d_in[3];
    const float* pos_compat = (const float*)d_in[4];
    const float* col_compat = (const float*)d_in[5];
    const float* weight     = (const float*)d_in[6];
    float* pred = (float*)d_out;
    float* ws   = (float*)d_ws;

    size_t o = 0;
    float* lg  = ws + o;  o += (size_t)BB*CC*PLF;   // 44 MB
    float* g   = ws + o;  o += (size_t)BB*NB*PLP;   // 15.9 MB
    float* cf  = ws + o;  o += (size_t)BB*3*PLP;    // 0.4 MB
    float* p   = ws + o;  o += (size_t)BB*CC*PLP;   // 2.75 MB
    float* msg = ws + o;                            // 2.75 MB

    const int TB = 256;
    hipLaunchKernelGGL(pool_img_k, dim3((BB*3*PLP+TB-1)/TB), dim3(TB), 0, stream,
                       img, col_schan, cf);
    hipLaunchKernelGGL(gauss_k, dim3((BB*NB*PLP+TB-1)/TB), dim3(TB), 0, stream,
                       cf, pos_sdims, pos_compat, col_compat, g);
    hipLaunchKernelGGL(lsm_pool_k, dim3(32, 32, BB), dim3(256), 0, stream,
                       unary, lg, p);
    for (int it = 0; it < NITER; ++it) {
        hipLaunchKernelGGL(msg_k, dim3(8, 16, BB*3), dim3(128), 0, stream,
                           g, p, msg);
        hipLaunchKernelGGL(combine_k, dim3(32, 32, BB), dim3(256), 0, stream,
                           msg, lg, weight, p, pred, (it == NITER-1) ? 1 : 0);
    }
}

// Round 3
// 356.538 us; speedup vs baseline: 1.4856x; 1.0275x over previous
//
#include <hip/hip_runtime.h>
#include <cmath>

// GaussCRF on MI355X — round 3.
// B=2, C=21, H=W=512, blur=4 -> h=w=128, K=11 (121 shifts), 5 iterations.
//
// vs round 2:
//  * lg buffer eliminated: combine/init read unary and recompute log-softmax
//    inline (saves 44 MB write + one kernel; unary stays L3-hot).
//  * msg_k v3: one thread per position owning ALL 21 channels; p tile staged
//    channel-fastest pt[18][26][28] so each of the 121 taps is 5x ds_read_b128
//    + 1x b32; g read exactly once (coalesced per-ij); 2 ij-halves per block
//    reduced through LDS. ~2x LDS efficiency + 3x less g traffic vs round 2.

#define BB 2
#define CC 21
#define HH 512
#define WW 512
#define HP 128
#define WP 128
#define KF 11
#define SPAN 5
#define NB 121
#define NITER 5
#define PLF (HH*WW)
#define PLP (HP*WP)
#define TCH 28    // padded channel stride in msg LDS tile (16B-aligned, 2-way banks)

__global__ void pool_img_k(const float* __restrict__ img,
                           const float* __restrict__ col_schan,
                           float* __restrict__ cf) {
    int idx = blockIdx.x * blockDim.x + threadIdx.x;
    if (idx >= BB*3*PLP) return;
    int Y  = idx & (WP-1);
    int X  = (idx >> 7) & (HP-1);
    int bc = idx >> 14;                       // b*3 + c
    const float* base = img + ((size_t)bc*HH + X*4)*WW + Y*4;
    float s = 0.f;
    #pragma unroll
    for (int i = 0; i < 4; ++i)
        #pragma unroll
        for (int j = 0; j < 4; ++j)
            s += base[i*WW + j];
    cf[idx] = s * (1.f/16.f) * col_schan[0];
}

// one thread per (b, ij, X, Y); g layout [b][ij][X][Y]
__global__ void gauss_k(const float* __restrict__ cf,
                        const float* __restrict__ pos_sdims,
                        const float* __restrict__ pos_compat,
                        const float* __restrict__ col_compat,
                        float* __restrict__ g) {
    int idx = blockIdx.x * blockDim.x + threadIdx.x;
    if (idx >= BB*NB*PLP) return;
    int xy = idx & (PLP-1);
    int t  = idx >> 14;
    int ij = t % NB;
    int b  = t / NB;
    int Y = xy & (WP-1);
    int X = xy >> 7;
    int di = ij / KF - SPAN;
    int dj = ij % KF - SPAN;
    int Xn = X + di, Yn = Y + dj;
    float val = 0.f;
    if (Xn >= 0 && Xn < HP && Yn >= 0 && Yn < WP) {
        const float* cb = cf + (size_t)b*3*PLP;
        int o0 = xy, o = Xn*WP + Yn;
        float d0 = cb[o]         - cb[o0];
        float d1 = cb[PLP + o]   - cb[PLP + o0];
        float d2 = cb[2*PLP + o] - cb[2*PLP + o0];
        float cd2 = d0*d0 + d1*d1 + d2*d2;
        float ps  = 4.f * pos_sdims[0];
        float pd2 = ps*ps * (float)(di*di + dj*dj);
        val = pos_compat[0] * expf(-0.5f*pd2) + col_compat[0] * expf(-0.5f*cd2);
    }
    g[idx] = val;
}

// p0 = 4x4 pool of log_softmax(unary); nothing else materialized.
__global__ __launch_bounds__(256) void init_p_k(const float* __restrict__ unary,
                                                float* __restrict__ p) {
    int b  = blockIdx.z;
    int tx = blockIdx.y, ty = blockIdx.x;     // 32 x 32 tiles of 16x16
    int l  = threadIdx.x;
    int row = l >> 4, col = l & 15;
    int x = tx*16 + row, y = ty*16 + col;
    size_t base = (size_t)b*CC*PLF + (size_t)x*WW + y;
    float v[CC];
    float m = -1e30f;
    #pragma unroll
    for (int c = 0; c < CC; ++c) { v[c] = unary[base + (size_t)c*PLF]; m = fmaxf(m, v[c]); }
    float s = 0.f;
    #pragma unroll
    for (int c = 0; c < CC; ++c) s += expf(v[c]-m);
    float ls = m + logf(s);
    int X = tx*4 + (row>>2), Y = ty*4 + (col>>2);
    size_t pb = (size_t)b*CC*PLP + (size_t)X*WP + Y;
    bool wr = (l & 51) == 0;                  // lane bits {0,1,4,5} == 0
    #pragma unroll
    for (int c = 0; c < CC; ++c) {
        float sm = v[c] - ls;
        sm += __shfl_xor(sm, 1);
        sm += __shfl_xor(sm, 2);
        sm += __shfl_xor(sm, 16);
        sm += __shfl_xor(sm, 32);
        if (wr) p[pb + (size_t)c*PLP] = sm * (1.f/16.f);
    }
}

// msg[b,c,X,Y] = sum_ij g[b,ij,X,Y] * p[b,c,X+di-5,Y+dj-5]
// block: 128 positions (8x16) x 2 ij-halves = 256 threads; grid (8,16,BB).
__global__ __launch_bounds__(256) void msg_k(const float* __restrict__ g,
                                             const float* __restrict__ p,
                                             float* __restrict__ msg) {
    int b  = blockIdx.z;
    int tx = blockIdx.y;                      // 0..15 (row tiles of 8)
    int ty = blockIdx.x;                      // 0..7  (col tiles of 16)
    int tid = threadIdx.x;
    int pos = tid & 127;
    int half = tid >> 7;
    int x = pos >> 4;                         // 0..7
    int y = pos & 15;                         // 0..15
    __shared__ float pt[18][26][TCH];         // 52.4 KB
    const float* pb = p + (size_t)b*CC*PLP;
    int X0 = tx*8 - SPAN, Y0 = ty*16 - SPAN;
    for (int e = tid; e < CC*18*26; e += 256) {
        int c  = e / (18*26);
        int r  = (e / 26) % 18;
        int cl = e % 26;
        int gX = X0 + r, gY = Y0 + cl;
        float v = 0.f;
        if (gX >= 0 && gX < HP && gY >= 0 && gY < WP)
            v = pb[(size_t)c*PLP + gX*WP + gY];
        pt[r][cl][c] = v;
    }
    __syncthreads();
    int Xg = tx*8 + x, Yg = ty*16 + y;
    const float* gq = g + (size_t)b*NB*PLP + (size_t)Xg*WP + Yg;
    float acc[CC];
    #pragma unroll
    for (int c = 0; c < CC; ++c) acc[c] = 0.f;
    int ij0 = half ? 61 : 0;
    int nij = half ? 60 : 61;
    #pragma unroll 4
    for (int k = 0; k < nij; ++k) {
        int ij = ij0 + k;
        int di = ij / KF;
        int dj = ij - di*KF;
        float gv = gq[(size_t)ij*PLP];
        const float* sp = &pt[x+di][y+dj][0];
        const float4* q = (const float4*)sp;
        float4 q0 = q[0], q1 = q[1], q2 = q[2], q3 = q[3], q4 = q[4];
        float  q5 = sp[20];
        acc[0]  = fmaf(gv, q0.x, acc[0]);  acc[1]  = fmaf(gv, q0.y, acc[1]);
        acc[2]  = fmaf(gv, q0.z, acc[2]);  acc[3]  = fmaf(gv, q0.w, acc[3]);
        acc[4]  = fmaf(gv, q1.x, acc[4]);  acc[5]  = fmaf(gv, q1.y, acc[5]);
        acc[6]  = fmaf(gv, q1.z, acc[6]);  acc[7]  = fmaf(gv, q1.w, acc[7]);
        acc[8]  = fmaf(gv, q2.x, acc[8]);  acc[9]  = fmaf(gv, q2.y, acc[9]);
        acc[10] = fmaf(gv, q2.z, acc[10]); acc[11] = fmaf(gv, q2.w, acc[11]);
        acc[12] = fmaf(gv, q3.x, acc[12]); acc[13] = fmaf(gv, q3.y, acc[13]);
        acc[14] = fmaf(gv, q3.z, acc[14]); acc[15] = fmaf(gv, q3.w, acc[15]);
        acc[16] = fmaf(gv, q4.x, acc[16]); acc[17] = fmaf(gv, q4.y, acc[17]);
        acc[18] = fmaf(gv, q4.z, acc[18]); acc[19] = fmaf(gv, q4.w, acc[19]);
        acc[20] = fmaf(gv, q5,   acc[20]);
    }
    __syncthreads();                          // pt reads done; overlay reduction
    float* red = &pt[0][0][0];                // 128*21 floats
    if (half) {
        #pragma unroll
        for (int c = 0; c < CC; ++c) red[pos*CC + c] = acc[c];
    }
    __syncthreads();
    if (!half) {
        float* mb = msg + (size_t)b*CC*PLP + (size_t)Xg*WP + Yg;
        #pragma unroll
        for (int c = 0; c < CC; ++c)
            mb[(size_t)c*PLP] = acc[c] + red[pos*CC + c];
    }
}

// bilinear 4x upsample of msg + (1-w)*lg_unary + w*mu, with lg recomputed
// from unary inline; then softmax+pool -> p (iters 0..3) or write pred (last).
__global__ __launch_bounds__(256) void combine_k(const float* __restrict__ msg,
                                                 const float* __restrict__ unary,
                                                 const float* __restrict__ weight,
                                                 float* __restrict__ p,
                                                 float* __restrict__ pred,
                                                 int last) {
    int b  = blockIdx.z;
    int tx = blockIdx.y, ty = blockIdx.x;     // 32 x 32 tiles of 16x16
    int l  = threadIdx.x;
    int row = l >> 4, col = l & 15;
    __shared__ float ms[CC][6][6];
    const float* mb = msg + (size_t)b*CC*PLP;
    for (int t = l; t < CC*36; t += 256) {
        int c = t / 36, rr = (t / 6) % 6, cl = t % 6;
        int gX = tx*4 - 1 + rr; gX = gX < 0 ? 0 : (gX > HP-1 ? HP-1 : gX);
        int gY = ty*4 - 1 + cl; gY = gY < 0 ? 0 : (gY > WP-1 ? WP-1 : gY);
        ms[c][rr][cl] = mb[(size_t)c*PLP + gX*WP + gY];
    }
    __syncthreads();
    // half-pixel bilinear: u = x/4 - 0.375; fx per (x%4): {0.625,0.875,0.125,0.375}
    const float fw0 = 0.625f, fw1 = 0.875f, fw2 = 0.125f, fw3 = 0.375f;
    int r  = row & 3, q  = row >> 2;
    int rc = col & 3, qc = col >> 2;
    float fx = (r  == 0) ? fw0 : (r  == 1) ? fw1 : (r  == 2) ? fw2 : fw3;
    float fy = (rc == 0) ? fw0 : (rc == 1) ? fw1 : (rc == 2) ? fw2 : fw3;
    int i0 = q  + (r  >> 1);
    int j0 = qc + (rc >> 1);
    float w00 = (1.f-fx)*(1.f-fy), w01 = (1.f-fx)*fy;
    float w10 = fx*(1.f-fy),       w11 = fx*fy;
    int x = tx*16 + row, y = ty*16 + col;
    size_t base = (size_t)b*CC*PLF + (size_t)x*WW + y;
    float v[CC];
    float m = -1e30f;
    #pragma unroll
    for (int c = 0; c < CC; ++c) { v[c] = unary[base + (size_t)c*PLF]; m = fmaxf(m, v[c]); }
    float s = 0.f;
    #pragma unroll
    for (int c = 0; c < CC; ++c) s += expf(v[c]-m);
    float ls = m + logf(s);
    float wt = weight[0], uw = 1.f - wt;      // UNARY_WEIGHT = 1.0
    float val[CC];
    #pragma unroll
    for (int c = 0; c < CC; ++c) {
        float mu = w00*ms[c][i0][j0]   + w01*ms[c][i0][j0+1]
                 + w10*ms[c][i0+1][j0] + w11*ms[c][i0+1][j0+1];
        val[c] = uw*(v[c]-ls) + wt*mu;
    }
    if (!last) {
        float mm = -1e30f;
        #pragma unroll
        for (int c = 0; c < CC; ++c) mm = fmaxf(mm, val[c]);
        float ss = 0.f;
        #pragma unroll
        for (int c = 0; c < CC; ++c) { float e = expf(val[c]-mm); val[c] = e; ss += e; }
        float inv = 1.f/ss;
        int X = tx*4 + q, Y = ty*4 + qc;
        size_t pb = (size_t)b*CC*PLP + (size_t)X*WP + Y;
        bool wr = (l & 51) == 0;
        #pragma unroll
        for (int c = 0; c < CC; ++c) {
            float sm = val[c]*inv;
            sm += __shfl_xor(sm, 1);
            sm += __shfl_xor(sm, 2);
            sm += __shfl_xor(sm, 16);
            sm += __shfl_xor(sm, 32);
            if (wr) p[pb + (size_t)c*PLP] = sm * (1.f/16.f);
        }
    } else {
        #pragma unroll
        for (int c = 0; c < CC; ++c)
            pred[base + (size_t)c*PLF] = val[c];
    }
}

extern "C" void kernel_launch(void* const* d_in, const int* in_sizes, int n_in,
                              void* d_out, int out_size, void* d_ws, size_t ws_size,
                              hipStream_t stream) {
    const float* unary      = (const float*)d_in[0];
    const float* img        = (const float*)d_in[1];
    const float* pos_sdims  = (const float*)d_in[2];
    const float* col_schan  = (const float*)d_in[3];
    const float* pos_compat = (const float*)d_in[4];
    const float* col_compat = (const float*)d_in[5];
    const float* weight     = (const float*)d_in[6];
    float* pred = (float*)d_out;
    float* ws   = (float*)d_ws;

    size_t o = 0;
    float* g   = ws + o;  o += (size_t)BB*NB*PLP;   // 15.9 MB
    float* cf  = ws + o;  o += (size_t)BB*3*PLP;    // 0.4 MB
    float* p   = ws + o;  o += (size_t)BB*CC*PLP;   // 2.75 MB
    float* msg = ws + o;                            // 2.75 MB

    const int TB = 256;
    hipLaunchKernelGGL(pool_img_k, dim3((BB*3*PLP+TB-1)/TB), dim3(TB), 0, stream,
                       img, col_schan, cf);
    hipLaunchKernelGGL(gauss_k, dim3((BB*NB*PLP+TB-1)/TB), dim3(TB), 0, stream,
                       cf, pos_sdims, pos_compat, col_compat, g);
    hipLaunchKernelGGL(init_p_k, dim3(32, 32, BB), dim3(256), 0, stream,
                       unary, p);
    for (int it = 0; it < NITER; ++it) {
        hipLaunchKernelGGL(msg_k, dim3(8, 16, BB), dim3(256), 0, stream,
                           g, p, msg);
        hipLaunchKernelGGL(combine_k, dim3(32, 32, BB), dim3(256), 0, stream,
                           msg, unary, weight, p, pred, (it == NITER-1) ? 1 : 0);
    }
}